// Round 2
// baseline (269.153 us; speedup 1.0000x reference)
//
#include <hip/hip_runtime.h>
#include <hip/hip_cooperative_groups.h>

namespace cg = cooperative_groups;

// Problem constants
#define BATCH   8
#define NNODES  16384
#define KNBR    16
#define LATENT  128
#define DOUT    32
#define NROWS   (BATCH * NNODES)          // 131072 rows

typedef __attribute__((ext_vector_type(8))) short short8;   // 8 bf16 (4 VGPRs)
typedef __attribute__((ext_vector_type(4))) float floatx4;  // MFMA acc

__device__ __forceinline__ unsigned short f2bf(float f) {   // fp32 -> bf16 RNE
    unsigned u = __float_as_uint(f);
    u += 0x7fff + ((u >> 16) & 1);
    return (unsigned short)(u >> 16);
}

__device__ __forceinline__ float dot2bf(unsigned a, unsigned b) {
    float alo = __uint_as_float(a << 16);
    float ahi = __uint_as_float(a & 0xffff0000u);
    float blo = __uint_as_float(b << 16);
    float bhi = __uint_as_float(b & 0xffff0000u);
    return alo * blo + ahi * bhi;
}

// Direct global->LDS 16B copy (no VGPR round-trip). Size must be a literal.
__device__ __forceinline__ void gload_lds16(const float* g, void* l) {
    __builtin_amdgcn_global_load_lds(
        (const __attribute__((address_space(1))) void*)g,
        (__attribute__((address_space(3))) void*)l,
        16, 0, 0);
}

#define BPAD 136    // B row stride: 128 + 8 bf16 (272 B) -> 2-way (free) reads

// ---------------------------------------------------------------------------
// Fused persistent cooperative kernel.
// Phase A (proj): BM=64 tiles, grid-strided. Tile->block mapping keeps batch b
//   on blocks bid%8==b so batch b's table lines are written (and thus L2-
//   resident) on the same XCD that gathers them in phase B.
//   A staged fp32 via global_load_lds(16B) with XOR swizzle on BOTH sides
//   (pre-swizzled global source + swizzled ds_read, rule #21):
//     phys(L) = L ^ ((row&7)<<4), involution within each 512 B row.
// grid.sync() (cooperative) -- guaranteed co-resident: grid = occ * 256 CUs.
// Phase B (gather+dot): cooperative-4, identical proven body, grid-strided
//   with stride % 8 == 0 so batch == bid%8 is preserved.
// ---------------------------------------------------------------------------
__global__ __launch_bounds__(256) void fused_kernel(
    const float* __restrict__ feats,
    const float* __restrict__ kw, const float* __restrict__ kb,
    const float* __restrict__ qw, const float* __restrict__ qb,
    const int* __restrict__ idx, float* __restrict__ out,
    unsigned short* __restrict__ tkb, unsigned short* __restrict__ tqb)
{
    __shared__ __align__(16) unsigned char A_raw[64 * 512]; // 32 KB fp32 tile
    __shared__ unsigned short B_lds[64 * BPAD];             // 17 KB
    __shared__ float bias_lds[64];

    const int tid  = threadIdx.x;
    const int lane = tid & 63;
    const int w    = tid >> 6;                     // wave 0..3
    const int bid  = blockIdx.x;
    const int nb   = gridDim.x;                    // multiple of 256 (so of 8)

    // Stage B = [kw ; qw] as bf16 + bias, once per persistent block.
    {
        const float4* kw4 = (const float4*)kw;     // [32 rows][32 f4]
        const float4* qw4 = (const float4*)qw;
#pragma unroll
        for (int i = 0; i < 8; ++i) {
            const int linear = i * 256 + tid;      // 0..2047
            const int row = linear >> 5;           // 0..63
            const int c4  = linear & 31;
            const float4 v = (row < 32) ? kw4[row * 32 + c4] : qw4[(row - 32) * 32 + c4];
            unsigned lo = f2bf(v.x) | ((unsigned)f2bf(v.y) << 16);
            unsigned hi = f2bf(v.z) | ((unsigned)f2bf(v.w) << 16);
            *(uint2*)&B_lds[row * BPAD + c4 * 4] = make_uint2(lo, hi);
        }
        if (tid < 64) bias_lds[tid] = (tid < 32) ? kb[tid] : qb[tid - 32];
    }

    const int m = lane & 15;   // MFMA row (A) / col (B,C)
    const int q = lane >> 4;   // quad

    // ---------------- Phase A: projection ----------------
    const int bgrp = nb >> 3;          // blocks per batch-group
    const int bat  = bid & 7;          // this block's batch (== its XCD, mod 8)
    for (int u = bid >> 3; u < 256; u += bgrp) {
        const long long blk_row = ((long long)bat * 256 + u) * 64;
        __syncthreads();   // prev tile consumed (j=0: B/bias staged)

        // Stage A tile: 64 rows x 128 fp32 = 32 KB, 8 x 16B per thread.
        // Dest L linear (wave-uniform base + lane*16); source address is the
        // element whose swizzled position is L.
#pragma unroll
        for (int i = 0; i < 8; ++i) {
            const int L  = i * 4096 + tid * 16;
            const int r  = L >> 9;                              // row 0..63
            const int c0 = ((L & 511) ^ ((r & 7) << 4)) >> 2;   // fp32 col
            gload_lds16(feats + (blk_row + r) * 128 + c0, A_raw + L);
        }
        __syncthreads();   // drains vmcnt -> tile visible

        floatx4 acc[4];
#pragma unroll
        for (int ct = 0; ct < 4; ++ct) acc[ct] = (floatx4){0.f, 0.f, 0.f, 0.f};

        const int rloc = w * 16 + m;       // A row 0..63
        const int sw   = (rloc & 7) << 4;
#pragma unroll
        for (int ks = 0; ks < 4; ++ks) {
            const int b0 = rloc * 512 + ks * 128 + q * 32;  // logical byte
            const int p0 = b0 ^ sw;                         // swizzled
            const float4 a0 = *(const float4*)(A_raw + p0);
            const float4 a1 = *(const float4*)(A_raw + (p0 ^ 16));
            union { short8 s; unsigned uu[4]; } af;
            af.uu[0] = f2bf(a0.x) | ((unsigned)f2bf(a0.y) << 16);
            af.uu[1] = f2bf(a0.z) | ((unsigned)f2bf(a0.w) << 16);
            af.uu[2] = f2bf(a1.x) | ((unsigned)f2bf(a1.y) << 16);
            af.uu[3] = f2bf(a1.z) | ((unsigned)f2bf(a1.w) << 16);
            const int kg = ks * 32 + q * 8;
#pragma unroll
            for (int ct = 0; ct < 4; ++ct) {
                const short8 bf = *(const short8*)&B_lds[(ct * 16 + m) * BPAD + kg];
                acc[ct] = __builtin_amdgcn_mfma_f32_16x16x32_bf16(af.s, bf, acc[ct], 0, 0, 0);
            }
        }

        // Epilogue: bias + bf16 store. C/D layout: col = lane&15, row = q*4+reg.
#pragma unroll
        for (int reg = 0; reg < 4; ++reg) {
            const long long row = blk_row + w * 16 + q * 4 + reg;
#pragma unroll
            for (int ct = 0; ct < 4; ++ct) {
                const float val = acc[ct][reg] + bias_lds[ct * 16 + m];
                if (ct < 2) tkb[row * DOUT + ct * 16 + m]       = f2bf(val);
                else        tqb[row * DOUT + (ct - 2) * 16 + m] = f2bf(val);
            }
        }
    }

    cg::this_grid().sync();   // tables complete + device-scope visibility

    // ---------------- Phase B: gather + scaled dot ----------------
    const long long NK  = (long long)NNODES * KNBR;     // 262144 per batch
    const long long BNK = NK * BATCH;                   // 2097152 total
    const int grp = tid >> 2;   // 0..63: output within pass
    const int j   = tid & 3;    // uint4 column within the 64B row

    const uint4* tb_k = (const uint4*)(tkb + (long long)bat * NNODES * DOUT);
    const uint4* tb_q = (const uint4*)(tqb + (long long)bat * NNODES * DOUT);

    for (int g = bid; g < 8192; g += nb) {              // g % 8 == bat
        const int blk = g >> 3;
#pragma unroll
        for (int p = 0; p < 4; ++p) {
            const long long local = (long long)blk * 256 + p * 64 + grp;  // < NK
            const long long o     = (long long)bat * NK + local;

            const int xi = __builtin_nontemporal_load(&idx[BNK + o]);        // ch 1
            const int yi = __builtin_nontemporal_load(&idx[2 * BNK + o]);    // ch 2

            const uint4 x = tb_k[(long long)xi * 4 + j];
            const uint4 y = tb_q[(long long)yi * 4 + j];
            float s = dot2bf(x.x, y.x) + dot2bf(x.y, y.y)
                    + dot2bf(x.z, y.z) + dot2bf(x.w, y.w);
            s += __shfl_xor(s, 1);
            s += __shfl_xor(s, 2);
            if (j == 0)
                __builtin_nontemporal_store(s * 0.17677669529663687f, &out[o]); // 32^-0.5
        }
    }
}

// ---------------------------------------------------------------------------
extern "C" void kernel_launch(void* const* d_in, const int* in_sizes, int n_in,
                              void* d_out, int out_size, void* d_ws, size_t ws_size,
                              hipStream_t stream)
{
    const float* feats = (const float*)d_in[0];
    const float* kw    = (const float*)d_in[1];
    const float* kb    = (const float*)d_in[2];
    const float* qw    = (const float*)d_in[3];
    const float* qb    = (const float*)d_in[4];
    const int*   idx   = (const int*)d_in[5];
    float*       out   = (float*)d_out;

    // Workspace: two bf16 tables [B*N, 32] = 8 MB each
    unsigned short* tkb = (unsigned short*)d_ws;
    unsigned short* tqb = tkb + (long long)NROWS * DOUT;

    // Co-residency-guaranteed grid for the cooperative launch.
    // LDS 49.6 KB/block -> expect occ = 3 (768 blocks); query to be safe.
    int occ = 0;
    if (hipOccupancyMaxActiveBlocksPerMultiprocessor(&occ, fused_kernel, 256, 0)
            != hipSuccess || occ < 1) occ = 2;
    if (occ > 3) occ = 3;
    const int nb = occ * 256;   // multiple of 256 -> multiple of 8

    void* args[] = {(void*)&feats, (void*)&kw, (void*)&kb, (void*)&qw, (void*)&qb,
                    (void*)&idx, (void*)&out, (void*)&tkb, (void*)&tqb};
    hipLaunchCooperativeKernel(fused_kernel, dim3(nb), dim3(256), args, 0, stream);
}

// Round 3
// 163.921 us; speedup vs baseline: 1.6420x; 1.6420x over previous
//
#include <hip/hip_runtime.h>

// Problem constants
#define BATCH   8
#define NNODES  16384
#define KNBR    16
#define LATENT  128
#define DOUT    32
#define NROWS   (BATCH * NNODES)          // 131072 rows

typedef __attribute__((ext_vector_type(8))) short short8;   // 8 bf16 (4 VGPRs)
typedef __attribute__((ext_vector_type(4))) float floatx4;  // MFMA acc

__device__ __forceinline__ unsigned short f2bf(float f) {   // fp32 -> bf16 RNE
    unsigned u = __float_as_uint(f);
    u += 0x7fff + ((u >> 16) & 1);
    return (unsigned short)(u >> 16);
}

__device__ __forceinline__ float dot2bf(unsigned a, unsigned b) {
    float alo = __uint_as_float(a << 16);
    float ahi = __uint_as_float(a & 0xffff0000u);
    float blo = __uint_as_float(b << 16);
    float bhi = __uint_as_float(b & 0xffff0000u);
    return alo * blo + ahi * bhi;
}

// Direct global->LDS 16B copy (no VGPR round-trip). Size must be a literal.
__device__ __forceinline__ void gload_lds16(const float* g, void* l) {
    __builtin_amdgcn_global_load_lds(
        (const __attribute__((address_space(1))) void*)g,
        (__attribute__((address_space(3))) void*)l,
        16, 0, 0);
}

#define BPAD 136    // B row stride: 128 + 8 bf16 (272 B)

// ---------------------------------------------------------------------------
// Kernel 1: bf16 MFMA projection (round-1 v3 structure, proven).
// 128 rows/block, 4 waves. A staged fp32 via global_load_lds(16B), XOR swizzle
// on BOTH sides (pre-swizzled global source + swizzled ds_read, rule #21):
//   phys(L) = L ^ ((row&7)<<4).
// NEW: tile->batch remap. Block bid handles batch bid%8, tile (bid>>3) within
// the batch, so batch b's table lines are written on block-residue b -- the
// same residue (-> same XCD under round-robin dispatch) that gathers batch b
// in kernel 2. Tables stay XCD-local in L2 instead of cross-XCD dirty.
// ---------------------------------------------------------------------------
__global__ __launch_bounds__(256) void proj_kernel(
    const float* __restrict__ feats,
    const float* __restrict__ kw, const float* __restrict__ kb,
    const float* __restrict__ qw, const float* __restrict__ qb,
    unsigned short* __restrict__ tkb, unsigned short* __restrict__ tqb)
{
    __shared__ __align__(16) unsigned char A_raw[128 * 256]; // 32 KB fp32 chunk
    __shared__ unsigned short B_lds[64 * BPAD];              // 17 KB
    __shared__ float bias_lds[64];

    const int tid  = threadIdx.x;
    const int lane = tid & 63;
    const int w    = tid >> 6;                     // wave 0..3
    const int bat  = blockIdx.x & 7;               // batch == block residue
    const int u    = blockIdx.x >> 3;              // tile within batch, 0..127
    const long long blk_row = (long long)bat * NNODES + (long long)u * 128;

    // Stage B = [kw ; qw] as bf16: B_lds[col*BPAD + k] = W_cat[col][k]
    {
        const float4* kw4 = (const float4*)kw;     // [32 rows][32 f4]
        const float4* qw4 = (const float4*)qw;
#pragma unroll
        for (int i = 0; i < 8; ++i) {
            const int linear = i * 256 + tid;      // 0..2047
            const int row = linear >> 5;           // 0..63
            const int c4  = linear & 31;
            const float4 v = (row < 32) ? kw4[row * 32 + c4] : qw4[(row - 32) * 32 + c4];
            unsigned lo = f2bf(v.x) | ((unsigned)f2bf(v.y) << 16);
            unsigned hi = f2bf(v.z) | ((unsigned)f2bf(v.w) << 16);
            *(uint2*)&B_lds[row * BPAD + c4 * 4] = make_uint2(lo, hi);
        }
        if (tid < 64) bias_lds[tid] = (tid < 32) ? kb[tid] : qb[tid - 32];
    }

    const int m = lane & 15;   // MFMA row (A) / col (B,C)
    const int q = lane >> 4;   // quad

    floatx4 acc[2][4];
#pragma unroll
    for (int rt = 0; rt < 2; ++rt)
#pragma unroll
        for (int ct = 0; ct < 4; ++ct) acc[rt][ct] = (floatx4){0.f, 0.f, 0.f, 0.f};

    for (int ch = 0; ch < 2; ++ch) {
        if (ch) __syncthreads();   // prev chunk fully consumed before overwrite

        // Issue A-chunk staging: 128 rows x 64 fp32 = 32 KB, 8 x 16B/thread.
        // Dest L linear; source address is the element whose swizzled
        // position is L: col_bytes = (L&255) ^ ((row&7)<<4).
#pragma unroll
        for (int i = 0; i < 8; ++i) {
            const int L  = i * 4096 + tid * 16;
            const int r  = L >> 8;                              // 0..127
            const int c0 = (((L & 255) ^ ((r & 7) << 4)) >> 2); // fp32 col
            gload_lds16(feats + (blk_row + r) * 128 + ch * 64 + c0, A_raw + L);
        }
        __syncthreads();   // drains vmcnt -> chunk (and on ch0: B/bias) visible

#pragma unroll
        for (int ks = 0; ks < 2; ++ks) {
            const int kg = ch * 64 + ks * 32 + q * 8;  // global k for B
            short8 bf[4];
#pragma unroll
            for (int ct = 0; ct < 4; ++ct)
                bf[ct] = *(const short8*)&B_lds[(ct * 16 + m) * BPAD + kg];
#pragma unroll
            for (int rt = 0; rt < 2; ++rt) {
                const int rloc = w * 32 + rt * 16 + m;
                const int b0   = rloc * 256 + ks * 128 + q * 32;   // logical byte
                const int p0   = b0 ^ ((rloc & 7) << 4);           // swizzled
                const float4 a0 = *(const float4*)(A_raw + p0);
                const float4 a1 = *(const float4*)(A_raw + (p0 ^ 16));
                union { short8 s; unsigned uu[4]; } af;
                af.uu[0] = f2bf(a0.x) | ((unsigned)f2bf(a0.y) << 16);
                af.uu[1] = f2bf(a0.z) | ((unsigned)f2bf(a0.w) << 16);
                af.uu[2] = f2bf(a1.x) | ((unsigned)f2bf(a1.y) << 16);
                af.uu[3] = f2bf(a1.z) | ((unsigned)f2bf(a1.w) << 16);
#pragma unroll
                for (int ct = 0; ct < 4; ++ct)
                    acc[rt][ct] = __builtin_amdgcn_mfma_f32_16x16x32_bf16(af.s, bf[ct], acc[rt][ct], 0, 0, 0);
            }
        }
    }

    // Epilogue: bias + bf16 store. C/D layout: col = lane&15, row = q*4+reg.
#pragma unroll
    for (int rt = 0; rt < 2; ++rt) {
#pragma unroll
        for (int reg = 0; reg < 4; ++reg) {
            const long long row = blk_row + w * 32 + rt * 16 + q * 4 + reg;
#pragma unroll
            for (int ct = 0; ct < 4; ++ct) {
                const float val = acc[rt][ct][reg] + bias_lds[ct * 16 + m];
                if (ct < 2) tkb[row * DOUT + ct * 16 + m]       = f2bf(val);
                else        tqb[row * DOUT + (ct - 2) * 16 + m] = f2bf(val);
            }
        }
    }
}

// ---------------------------------------------------------------------------
// Kernel 2: gather + scaled dot, ONE OUTPUT PER LANE.
// idx loads: stride-1 coalesced (4B/lane). Table rows: 4 independent
// dwordx4 per row, 8 loads in flight per pass, L2-resident (2.1 MB/batch,
// XCD-local thanks to proj's remap). Full 32-dim dot in-lane; stores
// 256 B/wave coalesced. Nontemporal idx/out keeps tables L2-resident.
// ---------------------------------------------------------------------------
__global__ __launch_bounds__(256) void gather_dot_kernel(
    const unsigned short* __restrict__ tkb, const unsigned short* __restrict__ tqb,
    const int* __restrict__ idx, float* __restrict__ out)
{
    const long long NK  = (long long)NNODES * KNBR;     // 262144 per batch
    const long long BNK = NK * BATCH;                   // 2097152 total

    const int bat = blockIdx.x & 7;
    const int blk = blockIdx.x >> 3;                    // 0..255
    const int tid = threadIdx.x;

    const uint4* tb_k = (const uint4*)(tkb + (long long)bat * NNODES * DOUT);
    const uint4* tb_q = (const uint4*)(tqb + (long long)bat * NNODES * DOUT);

#pragma unroll
    for (int p = 0; p < 4; ++p) {
        const long long local = (long long)blk * 1024 + p * 256 + tid;  // < NK
        const long long o     = (long long)bat * NK + local;

        const int xi = __builtin_nontemporal_load(&idx[BNK + o]);        // ch 1
        const int yi = __builtin_nontemporal_load(&idx[2 * BNK + o]);    // ch 2

        const uint4* xr = tb_k + (long long)xi * 4;
        const uint4* yr = tb_q + (long long)yi * 4;
        const uint4 x0 = xr[0], x1 = xr[1], x2 = xr[2], x3 = xr[3];
        const uint4 y0 = yr[0], y1 = yr[1], y2 = yr[2], y3 = yr[3];

        float s = dot2bf(x0.x, y0.x) + dot2bf(x0.y, y0.y)
                + dot2bf(x0.z, y0.z) + dot2bf(x0.w, y0.w)
                + dot2bf(x1.x, y1.x) + dot2bf(x1.y, y1.y)
                + dot2bf(x1.z, y1.z) + dot2bf(x1.w, y1.w)
                + dot2bf(x2.x, y2.x) + dot2bf(x2.y, y2.y)
                + dot2bf(x2.z, y2.z) + dot2bf(x2.w, y2.w)
                + dot2bf(x3.x, y3.x) + dot2bf(x3.y, y3.y)
                + dot2bf(x3.z, y3.z) + dot2bf(x3.w, y3.w);

        __builtin_nontemporal_store(s * 0.17677669529663687f, &out[o]);  // 32^-0.5
    }
}

// ---------------------------------------------------------------------------
extern "C" void kernel_launch(void* const* d_in, const int* in_sizes, int n_in,
                              void* d_out, int out_size, void* d_ws, size_t ws_size,
                              hipStream_t stream)
{
    const float* feats = (const float*)d_in[0];
    const float* kw    = (const float*)d_in[1];
    const float* kb    = (const float*)d_in[2];
    const float* qw    = (const float*)d_in[3];
    const float* qb    = (const float*)d_in[4];
    const int*   idx   = (const int*)d_in[5];
    float*       out   = (float*)d_out;

    // Workspace: two bf16 tables [B*N, 32] = 8 MB each
    unsigned short* tkb = (unsigned short*)d_ws;
    unsigned short* tqb = tkb + (long long)NROWS * DOUT;

    proj_kernel<<<NROWS / 128, 256, 0, stream>>>(feats, kw, kb, qw, qb, tkb, tqb);
    gather_dot_kernel<<<(int)((long long)BATCH * NNODES * KNBR / 1024), 256, 0, stream>>>(
        tkb, tqb, idx, out);
}

// Round 4
// 143.959 us; speedup vs baseline: 1.8697x; 1.1387x over previous
//
#include <hip/hip_runtime.h>

// Problem constants
#define BATCH   8
#define NNODES  16384
#define KNBR    16
#define LATENT  128
#define DOUT    32
#define NROWS   (BATCH * NNODES)          // 131072 rows

typedef __attribute__((ext_vector_type(8))) short short8;   // 8 bf16 (4 VGPRs)
typedef __attribute__((ext_vector_type(4))) float floatx4;  // MFMA acc

__device__ __forceinline__ unsigned short f2bf(float f) {   // fp32 -> bf16 RNE
    unsigned u = __float_as_uint(f);
    u += 0x7fff + ((u >> 16) & 1);
    return (unsigned short)(u >> 16);
}

__device__ __forceinline__ float dot2bf(unsigned a, unsigned b) {
    float alo = __uint_as_float(a << 16);
    float ahi = __uint_as_float(a & 0xffff0000u);
    float blo = __uint_as_float(b << 16);
    float bhi = __uint_as_float(b & 0xffff0000u);
    return alo * blo + ahi * bhi;
}

// Direct global->LDS 16B copy (no VGPR round-trip). Size must be a literal.
__device__ __forceinline__ void gload_lds16(const float* g, void* l) {
    __builtin_amdgcn_global_load_lds(
        (const __attribute__((address_space(1))) void*)g,
        (__attribute__((address_space(3))) void*)l,
        16, 0, 0);
}

#define BPAD 136    // B row stride: 128 + 8 bf16 (272 B)

// ---------------------------------------------------------------------------
// Kernel 1: bf16 MFMA projection (proven round-1/3 structure).
// 128 rows/block, 4 waves. A staged fp32 via global_load_lds(16B), XOR swizzle
// on BOTH sides (pre-swizzled global source + swizzled ds_read, rule #21):
//   phys(L) = L ^ ((row&7)<<4).
// Tile->batch remap: block bid handles batch bid%8 so batch b's table lines
// are written on block-residue b -- the same residue (-> same XCD under
// round-robin dispatch) that gathers batch b in kernel 2. Tables (2 MiB/batch)
// stay XCD-local in the 4 MiB per-XCD L2.
// ---------------------------------------------------------------------------
__global__ __launch_bounds__(256) void proj_kernel(
    const float* __restrict__ feats,
    const float* __restrict__ kw, const float* __restrict__ kb,
    const float* __restrict__ qw, const float* __restrict__ qb,
    unsigned short* __restrict__ tkb, unsigned short* __restrict__ tqb)
{
    __shared__ __align__(16) unsigned char A_raw[128 * 256]; // 32 KB fp32 chunk
    __shared__ unsigned short B_lds[64 * BPAD];              // 17 KB
    __shared__ float bias_lds[64];

    const int tid  = threadIdx.x;
    const int lane = tid & 63;
    const int w    = tid >> 6;                     // wave 0..3
    const int bat  = blockIdx.x & 7;               // batch == block residue
    const int u    = blockIdx.x >> 3;              // tile within batch, 0..127
    const long long blk_row = (long long)bat * NNODES + (long long)u * 128;

    // Stage B = [kw ; qw] as bf16: B_lds[col*BPAD + k] = W_cat[col][k]
    {
        const float4* kw4 = (const float4*)kw;     // [32 rows][32 f4]
        const float4* qw4 = (const float4*)qw;
#pragma unroll
        for (int i = 0; i < 8; ++i) {
            const int linear = i * 256 + tid;      // 0..2047
            const int row = linear >> 5;           // 0..63
            const int c4  = linear & 31;
            const float4 v = (row < 32) ? kw4[row * 32 + c4] : qw4[(row - 32) * 32 + c4];
            unsigned lo = f2bf(v.x) | ((unsigned)f2bf(v.y) << 16);
            unsigned hi = f2bf(v.z) | ((unsigned)f2bf(v.w) << 16);
            *(uint2*)&B_lds[row * BPAD + c4 * 4] = make_uint2(lo, hi);
        }
        if (tid < 64) bias_lds[tid] = (tid < 32) ? kb[tid] : qb[tid - 32];
    }

    const int m = lane & 15;   // MFMA row (A) / col (B,C)
    const int q = lane >> 4;   // quad

    floatx4 acc[2][4];
#pragma unroll
    for (int rt = 0; rt < 2; ++rt)
#pragma unroll
        for (int ct = 0; ct < 4; ++ct) acc[rt][ct] = (floatx4){0.f, 0.f, 0.f, 0.f};

    for (int ch = 0; ch < 2; ++ch) {
        if (ch) __syncthreads();   // prev chunk fully consumed before overwrite

        // Issue A-chunk staging: 128 rows x 64 fp32 = 32 KB, 8 x 16B/thread.
        // Dest L linear; source address is the element whose swizzled
        // position is L: col_bytes = (L&255) ^ ((row&7)<<4).
#pragma unroll
        for (int i = 0; i < 8; ++i) {
            const int L  = i * 4096 + tid * 16;
            const int r  = L >> 8;                              // 0..127
            const int c0 = (((L & 255) ^ ((r & 7) << 4)) >> 2); // fp32 col
            gload_lds16(feats + (blk_row + r) * 128 + ch * 64 + c0, A_raw + L);
        }
        __syncthreads();   // drains vmcnt -> chunk (and on ch0: B/bias) visible

#pragma unroll
        for (int ks = 0; ks < 2; ++ks) {
            const int kg = ch * 64 + ks * 32 + q * 8;  // global k for B
            short8 bf[4];
#pragma unroll
            for (int ct = 0; ct < 4; ++ct)
                bf[ct] = *(const short8*)&B_lds[(ct * 16 + m) * BPAD + kg];
#pragma unroll
            for (int rt = 0; rt < 2; ++rt) {
                const int rloc = w * 32 + rt * 16 + m;
                const int b0   = rloc * 256 + ks * 128 + q * 32;   // logical byte
                const int p0   = b0 ^ ((rloc & 7) << 4);           // swizzled
                const float4 a0 = *(const float4*)(A_raw + p0);
                const float4 a1 = *(const float4*)(A_raw + (p0 ^ 16));
                union { short8 s; unsigned uu[4]; } af;
                af.uu[0] = f2bf(a0.x) | ((unsigned)f2bf(a0.y) << 16);
                af.uu[1] = f2bf(a0.z) | ((unsigned)f2bf(a0.w) << 16);
                af.uu[2] = f2bf(a1.x) | ((unsigned)f2bf(a1.y) << 16);
                af.uu[3] = f2bf(a1.z) | ((unsigned)f2bf(a1.w) << 16);
#pragma unroll
                for (int ct = 0; ct < 4; ++ct)
                    acc[rt][ct] = __builtin_amdgcn_mfma_f32_16x16x32_bf16(af.s, bf[ct], acc[rt][ct], 0, 0, 0);
            }
        }
    }

    // Epilogue: bias + bf16 store. C/D layout: col = lane&15, row = q*4+reg.
#pragma unroll
    for (int rt = 0; rt < 2; ++rt) {
#pragma unroll
        for (int reg = 0; reg < 4; ++reg) {
            const long long row = blk_row + w * 32 + rt * 16 + q * 4 + reg;
#pragma unroll
            for (int ct = 0; ct < 4; ++ct) {
                const float val = acc[rt][ct][reg] + bias_lds[ct * 16 + m];
                if (ct < 2) tkb[row * DOUT + ct * 16 + m]       = f2bf(val);
                else        tqb[row * DOUT + (ct - 2) * 16 + m] = f2bf(val);
            }
        }
    }
}

// ---------------------------------------------------------------------------
// Kernel 2: gather + scaled dot, cooperative-4 v2.
// Thread tid owns output blkbase+tid: idx loads stride-1 coalesced with ZERO
// redundancy, final store fully dense (256 B/wave). Each quad processes its 4
// consecutive outputs over 4 passes; the owning row index is broadcast
// in-register via __shfl within the quad. Table rows read cooperative-4
// (4 lanes x 16 B contiguous = one fully-consumed 64 B line per row; 16 rows
// per instruction) -- the access shape round-3 proved optimal. 8 table loads
// in flight per wave; tables L2-resident & XCD-local (proj remap).
// ---------------------------------------------------------------------------
__global__ __launch_bounds__(256) void gather_dot_kernel(
    const unsigned short* __restrict__ tkb, const unsigned short* __restrict__ tqb,
    const int* __restrict__ idx, float* __restrict__ out)
{
    const long long NK  = (long long)NNODES * KNBR;     // 262144 per batch
    const long long BNK = NK * BATCH;                   // 2097152 total

    const int bat  = blockIdx.x & 7;
    const int blk  = blockIdx.x >> 3;                   // 0..1023
    const int tid  = threadIdx.x;
    const int lane = tid & 63;
    const int j    = tid & 3;                           // uint4 column in row

    const uint4* tb_k = (const uint4*)(tkb + (long long)bat * NNODES * DOUT);
    const uint4* tb_q = (const uint4*)(tqb + (long long)bat * NNODES * DOUT);

    const long long o0 = (long long)bat * NK + (long long)blk * 256 + tid;

    const int xi = __builtin_nontemporal_load(&idx[BNK + o0]);        // ch 1
    const int yi = __builtin_nontemporal_load(&idx[2 * BNK + o0]);    // ch 2

    float r0, r1, r2, r3;
#pragma unroll
    for (int p = 0; p < 4; ++p) {
        const int xp = __shfl(xi, (lane & ~3) | p);   // quad-owner broadcast
        const int yp = __shfl(yi, (lane & ~3) | p);
        const uint4 x = tb_k[(long long)xp * 4 + j];
        const uint4 y = tb_q[(long long)yp * 4 + j];
        float s = dot2bf(x.x, y.x) + dot2bf(x.y, y.y)
                + dot2bf(x.z, y.z) + dot2bf(x.w, y.w);
        s += __shfl_xor(s, 1);
        s += __shfl_xor(s, 2);   // all 4 lanes hold the full 32-dim sum
        if      (p == 0) r0 = s;
        else if (p == 1) r1 = s;
        else if (p == 2) r2 = s;
        else             r3 = s;
    }
    // lane j stores pass-j's result -> dense contiguous store
    const float v = (j == 0) ? r0 : (j == 1) ? r1 : (j == 2) ? r2 : r3;
    __builtin_nontemporal_store(v * 0.17677669529663687f, &out[o0]);  // 32^-0.5
}

// ---------------------------------------------------------------------------
extern "C" void kernel_launch(void* const* d_in, const int* in_sizes, int n_in,
                              void* d_out, int out_size, void* d_ws, size_t ws_size,
                              hipStream_t stream)
{
    const float* feats = (const float*)d_in[0];
    const float* kw    = (const float*)d_in[1];
    const float* kb    = (const float*)d_in[2];
    const float* qw    = (const float*)d_in[3];
    const float* qb    = (const float*)d_in[4];
    const int*   idx   = (const int*)d_in[5];
    float*       out   = (float*)d_out;

    // Workspace: two bf16 tables [B*N, 32] = 8 MB each
    unsigned short* tkb = (unsigned short*)d_ws;
    unsigned short* tqb = tkb + (long long)NROWS * DOUT;

    proj_kernel<<<NROWS / 128, 256, 0, stream>>>(feats, kw, kb, qw, qb, tkb, tqb);
    gather_dot_kernel<<<(int)((long long)BATCH * NNODES * KNBR / 256), 256, 0, stream>>>(
        tkb, tqb, idx, out);
}